// Round 1
// baseline (1078.307 us; speedup 1.0000x reference)
//
#include <hip/hip_runtime.h>
#include <hip/hip_bf16.h>

#define N_NODES 50000
#define N_EDGES 1600000
#define IN_C 256
#define HID_C 256
#define OUT_C 10

typedef short bf16x8 __attribute__((ext_vector_type(8)));
typedef float f32x4 __attribute__((ext_vector_type(4)));

// ---------- CSR build ----------
__global__ void k_count(const int* __restrict__ dst, int* __restrict__ cnt) {
    int e = blockIdx.x * 256 + threadIdx.x;
    if (e < N_EDGES) atomicAdd(&cnt[dst[e]], 1);
}

__global__ __launch_bounds__(1024) void k_scan(const int* __restrict__ cnt,
                                               int* __restrict__ row_start,
                                               int* __restrict__ cursor) {
    __shared__ int lds[1024];
    __shared__ int total;
    if (threadIdx.x == 0) total = 0;
    __syncthreads();
    for (int base = 0; base < N_NODES; base += 1024) {
        int i = base + threadIdx.x;
        int v = (i < N_NODES) ? cnt[i] : 0;
        lds[threadIdx.x] = v;
        __syncthreads();
        for (int off = 1; off < 1024; off <<= 1) {
            int t = (threadIdx.x >= off) ? lds[threadIdx.x - off] : 0;
            __syncthreads();
            lds[threadIdx.x] += t;
            __syncthreads();
        }
        int incl = lds[threadIdx.x];
        int excl = incl - v;
        int t0 = total;  // read before thread 0 updates
        if (i < N_NODES) {
            row_start[i] = t0 + excl;
            cursor[i]    = t0 + excl;
        }
        __syncthreads();
        if (threadIdx.x == 0) total += lds[1023];
        __syncthreads();
    }
}

__global__ void k_fill(const int* __restrict__ src, const int* __restrict__ dst,
                       int* __restrict__ cursor, int* __restrict__ csr_src) {
    int e = blockIdx.x * 256 + threadIdx.x;
    if (e < N_EDGES) {
        int p = atomicAdd(&cursor[dst[e]], 1);
        csr_src[p] = src[e];
    }
}

// ---------- prep: fp32 -> bf16 ----------
__global__ void k_cvt_x(const float* __restrict__ x, __hip_bfloat16* __restrict__ xb) {
    int i = blockIdx.x * 256 + threadIdx.x;  // exactly N_NODES*IN_C threads
    xb[i] = __float2bfloat16(x[i]);
}

// Wt[n][k] = (n<256 ? W1l : W1r)[k][n%256], bf16, n in [0,512)
__global__ void k_prep_w(const float* __restrict__ W1l, const float* __restrict__ W1r,
                         __hip_bfloat16* __restrict__ Wt) {
    int idx = blockIdx.x * 256 + threadIdx.x;  // 512*256
    int n = idx >> 8, k = idx & 255;
    float v = (n < HID_C) ? W1l[k * HID_C + n] : W1r[k * HID_C + (n - HID_C)];
    Wt[idx] = __float2bfloat16(v);
}

// ---------- GEMM1: [Ab | Bh] = Xb @ [W1l | W1r] (+b1 on Bh half), bf16 MFMA ----------
__global__ __launch_bounds__(256) void k_gemm1(
        const __hip_bfloat16* __restrict__ Xb, const __hip_bfloat16* __restrict__ Wt,
        const float* __restrict__ b1,
        __hip_bfloat16* __restrict__ Ab, __hip_bfloat16* __restrict__ Bh) {
    int wave = threadIdx.x >> 6;
    int lane = threadIdx.x & 63;
    int r    = lane & 15;
    int quad = lane >> 4;
    int m0 = blockIdx.x * 16;                   // 3125 m-tiles
    int n0 = (blockIdx.y * 4 + wave) * 16;      // 32 n-tiles (N=512)

    const bf16x8* ap = reinterpret_cast<const bf16x8*>(Xb + (size_t)(m0 + r) * IN_C + quad * 8);
    const bf16x8* bp = reinterpret_cast<const bf16x8*>(Wt + (size_t)(n0 + r) * IN_C + quad * 8);

    f32x4 acc = {0.f, 0.f, 0.f, 0.f};
#pragma unroll
    for (int kk = 0; kk < IN_C / 32; ++kk) {
        bf16x8 a = ap[kk * 4];  // advance 32 elements per step
        bf16x8 b = bp[kk * 4];
        acc = __builtin_amdgcn_mfma_f32_16x16x32_bf16(a, b, acc, 0, 0, 0);
    }

    int col = n0 + r;
#pragma unroll
    for (int i = 0; i < 4; ++i) {
        int row = m0 + quad * 4 + i;
        float v = acc[i];
        if (col < HID_C) {
            Ab[(size_t)row * HID_C + col] = __float2bfloat16(v);
        } else {
            int c2 = col - HID_C;
            Bh[(size_t)row * HID_C + c2] = __float2bfloat16(v + b1[c2]);
        }
    }
}

// ---------- layer1 aggregation + relu: Bh <- relu(mean_gather(Ab) + Bh) ----------
__global__ __launch_bounds__(256) void k_agg1(
        const __hip_bfloat16* __restrict__ Ab, const int* __restrict__ row_start,
        const int* __restrict__ cnt, const int* __restrict__ csr_src,
        __hip_bfloat16* __restrict__ Bh) {
    int nid = blockIdx.x;
    int c = threadIdx.x;
    int rs = row_start[nid];
    int n  = cnt[nid];
    float sum = 0.f;
    for (int e = 0; e < n; ++e) {
        int s = csr_src[rs + e];
        sum += __bfloat162float(Ab[(size_t)s * HID_C + c]);
    }
    float inv = 1.f / fmaxf((float)n, 1.f);
    float h = sum * inv + __bfloat162float(Bh[(size_t)nid * HID_C + c]);
    Bh[(size_t)nid * HID_C + c] = __float2bfloat16(fmaxf(h, 0.f));
}

// ---------- GEMM2: C = h@W2l ; D = h@W2r + b2 (N=10 each, fp32 VALU) ----------
__global__ void k_gemm2(const __hip_bfloat16* __restrict__ h,
                        const float* __restrict__ W2l, const float* __restrict__ W2r,
                        const float* __restrict__ b2,
                        float* __restrict__ C, float* __restrict__ D) {
    int t = blockIdx.x * 256 + threadIdx.x;
    if (t >= N_NODES * 20) return;
    int row = t / 20, j = t % 20;
    int jj = (j < 10) ? j : j - 10;
    const float* W = (j < 10) ? W2l : W2r;
    const __hip_bfloat16* hr = h + (size_t)row * HID_C;
    float s = 0.f;
#pragma unroll 8
    for (int k = 0; k < HID_C; ++k)
        s += __bfloat162float(hr[k]) * W[k * OUT_C + jj];
    if (j < 10) C[row * OUT_C + jj] = s;
    else        D[row * OUT_C + jj] = s + b2[jj];
}

// ---------- layer2 aggregation + log_softmax ----------
__global__ __launch_bounds__(64) void k_agg2(
        const float* __restrict__ C, const float* __restrict__ D,
        const int* __restrict__ row_start, const int* __restrict__ cnt,
        const int* __restrict__ csr_src, float* __restrict__ out) {
    int nid = blockIdx.x;
    int lane = threadIdx.x;
    int rs = row_start[nid];
    int n  = cnt[nid];
    float s[OUT_C];
#pragma unroll
    for (int j = 0; j < OUT_C; ++j) s[j] = 0.f;
    for (int e = lane; e < n; e += 64) {
        const float* cr = C + (size_t)csr_src[rs + e] * OUT_C;
#pragma unroll
        for (int j = 0; j < OUT_C; ++j) s[j] += cr[j];
    }
#pragma unroll
    for (int j = 0; j < OUT_C; ++j)
        for (int off = 32; off > 0; off >>= 1)
            s[j] += __shfl_down(s[j], off, 64);
    if (lane == 0) {
        float inv = 1.f / fmaxf((float)n, 1.f);
        float z[OUT_C], mx = -1e30f;
#pragma unroll
        for (int j = 0; j < OUT_C; ++j) {
            z[j] = s[j] * inv + D[nid * OUT_C + j];
            mx = fmaxf(mx, z[j]);
        }
        float se = 0.f;
#pragma unroll
        for (int j = 0; j < OUT_C; ++j) se += expf(z[j] - mx);
        float lse = logf(se) + mx;
#pragma unroll
        for (int j = 0; j < OUT_C; ++j) out[(size_t)nid * OUT_C + j] = z[j] - lse;
    }
}

extern "C" void kernel_launch(void* const* d_in, const int* in_sizes, int n_in,
                              void* d_out, int out_size, void* d_ws, size_t ws_size,
                              hipStream_t stream) {
    const float* x   = (const float*)d_in[0];
    const int*   ei  = (const int*)d_in[1];   // (2, E) row-major int32
    const float* W1l = (const float*)d_in[2];
    const float* W1r = (const float*)d_in[3];
    const float* b1  = (const float*)d_in[4];
    const float* W2l = (const float*)d_in[5];
    const float* W2r = (const float*)d_in[6];
    const float* b2  = (const float*)d_in[7];
    float* out = (float*)d_out;
    const int* src = ei;
    const int* dst = ei + N_EDGES;

    char* w = (char*)d_ws;
    size_t off = 0;
    auto alloc = [&](size_t bytes) -> void* {
        void* p = w + off;
        off = (off + bytes + 255) & ~(size_t)255;
        return p;
    };
    __hip_bfloat16* Xb  = (__hip_bfloat16*)alloc((size_t)N_NODES * IN_C * 2);
    __hip_bfloat16* Wt  = (__hip_bfloat16*)alloc((size_t)2 * HID_C * IN_C * 2);
    __hip_bfloat16* Ab  = (__hip_bfloat16*)alloc((size_t)N_NODES * HID_C * 2);
    __hip_bfloat16* Bh  = (__hip_bfloat16*)alloc((size_t)N_NODES * HID_C * 2);
    float* Cbuf = (float*)alloc((size_t)N_NODES * OUT_C * 4);
    float* Dbuf = (float*)alloc((size_t)N_NODES * OUT_C * 4);
    int* cnt       = (int*)alloc((size_t)N_NODES * 4);
    int* row_start = (int*)alloc((size_t)N_NODES * 4);
    int* cursor    = (int*)alloc((size_t)N_NODES * 4);
    int* csr_src   = (int*)alloc((size_t)N_EDGES * 4);

    hipMemsetAsync(cnt, 0, (size_t)N_NODES * 4, stream);

    k_count<<<N_EDGES / 256, 256, 0, stream>>>(dst, cnt);
    k_scan<<<1, 1024, 0, stream>>>(cnt, row_start, cursor);
    k_fill<<<N_EDGES / 256, 256, 0, stream>>>(src, dst, cursor, csr_src);

    k_cvt_x<<<(N_NODES * IN_C) / 256, 256, 0, stream>>>(x, Xb);
    k_prep_w<<<(2 * HID_C * IN_C) / 256, 256, 0, stream>>>(W1l, W1r, Wt);

    k_gemm1<<<dim3(N_NODES / 16, 8), 256, 0, stream>>>(Xb, Wt, b1, Ab, Bh);
    k_agg1<<<N_NODES, 256, 0, stream>>>(Ab, row_start, cnt, csr_src, Bh);
    k_gemm2<<<(N_NODES * 20 + 255) / 256, 256, 0, stream>>>(Bh, W2l, W2r, b2, Cbuf, Dbuf);
    k_agg2<<<N_NODES, 64, 0, stream>>>(Cbuf, Dbuf, row_start, cnt, csr_src, out);
}

// Round 2
// 540.852 us; speedup vs baseline: 1.9937x; 1.9937x over previous
//
#include <hip/hip_runtime.h>
#include <hip/hip_bf16.h>

#define N_NODES 50000
#define N_EDGES 1600000
#define IN_C 256
#define HID_C 256
#define OUT_C 10
#define CD_STRIDE 32
#define SCAN_BLOCKS 196   // ceil(50000/256)

typedef short bf16x8 __attribute__((ext_vector_type(8)));
typedef float f32x4 __attribute__((ext_vector_type(4)));

static __device__ __forceinline__ float b2f(short v) {
    unsigned u = (unsigned)(unsigned short)v << 16;
    return __builtin_bit_cast(float, u);
}
static __device__ __forceinline__ short f2b(float f) {
    __hip_bfloat16 h = __float2bfloat16(f);
    return __builtin_bit_cast(short, h);
}

// ---------- CSR build ----------
__global__ void k_count(const int* __restrict__ dst, int* __restrict__ cnt) {
    int t = blockIdx.x * 256 + threadIdx.x;
    if (t < N_EDGES / 4) {
        int4 v = ((const int4*)dst)[t];
        atomicAdd(&cnt[v.x], 1);
        atomicAdd(&cnt[v.y], 1);
        atomicAdd(&cnt[v.z], 1);
        atomicAdd(&cnt[v.w], 1);
    }
}

static __device__ __forceinline__ int block_incl_scan(int v, int* lds4) {
    int lane = threadIdx.x & 63, wave = threadIdx.x >> 6;
#pragma unroll
    for (int off = 1; off < 64; off <<= 1) {
        int t = __shfl_up(v, off, 64);
        if (lane >= off) v += t;
    }
    if (lane == 63) lds4[wave] = v;
    __syncthreads();
    int add = 0;
#pragma unroll
    for (int w = 0; w < 3; ++w) if (w < wave) add += lds4[w];
    return v + add;
}

__global__ __launch_bounds__(256) void k_scan1(const int* __restrict__ cnt,
                                               int* __restrict__ row_start,
                                               int* __restrict__ blocksum) {
    __shared__ int lds4[4];
    int i = blockIdx.x * 256 + threadIdx.x;
    int v = (i < N_NODES) ? cnt[i] : 0;
    int incl = block_incl_scan(v, lds4);
    if (i < N_NODES) row_start[i] = incl - v;   // block-local exclusive
    if (threadIdx.x == 255) blocksum[blockIdx.x] = incl;
}

__global__ __launch_bounds__(256) void k_scan2(const int* __restrict__ blocksum,
                                               int* __restrict__ blockoff) {
    __shared__ int lds4[4];
    int i = threadIdx.x;
    int v = (i < SCAN_BLOCKS) ? blocksum[i] : 0;
    int incl = block_incl_scan(v, lds4);
    if (i < SCAN_BLOCKS) blockoff[i] = incl - v;  // exclusive
}

__global__ __launch_bounds__(256) void k_scan3(int* __restrict__ row_start,
                                               const int* __restrict__ blockoff,
                                               int* __restrict__ cursor) {
    int i = blockIdx.x * 256 + threadIdx.x;
    if (i < N_NODES) {
        int r = row_start[i] + blockoff[blockIdx.x];
        row_start[i] = r;
        cursor[i] = r;
    }
}

__global__ void k_fill(const int* __restrict__ src, const int* __restrict__ dst,
                       int* __restrict__ cursor, int* __restrict__ csr_src) {
    int t = blockIdx.x * 256 + threadIdx.x;
    if (t < N_EDGES / 4) {
        int4 s = ((const int4*)src)[t];
        int4 d = ((const int4*)dst)[t];
        int p;
        p = atomicAdd(&cursor[d.x], 1); csr_src[p] = s.x;
        p = atomicAdd(&cursor[d.y], 1); csr_src[p] = s.y;
        p = atomicAdd(&cursor[d.z], 1); csr_src[p] = s.z;
        p = atomicAdd(&cursor[d.w], 1); csr_src[p] = s.w;
    }
}

// ---------- prep ----------
__global__ void k_cvt_x(const float4* __restrict__ x, short4* __restrict__ xb) {
    int i = blockIdx.x * 256 + threadIdx.x;   // N_NODES*IN_C/4 threads exactly
    float4 v = x[i];
    short4 o = { f2b(v.x), f2b(v.y), f2b(v.z), f2b(v.w) };
    xb[i] = o;
}

// Wt[n][k], n in [0,512): n<256 -> W1l[k][n], else W1r[k][n-256]
__global__ void k_prep_w(const float* __restrict__ W1l, const float* __restrict__ W1r,
                         __hip_bfloat16* __restrict__ Wt) {
    int idx = blockIdx.x * 256 + threadIdx.x;  // 512*256
    int n = idx >> 8, k = idx & 255;
    float v = (n < HID_C) ? W1l[k * HID_C + n] : W1r[k * HID_C + (n - HID_C)];
    Wt[idx] = __float2bfloat16(v);
}

// Wt2[n][k], n in [0,32): n<10 -> W2l[k][n]; 16<=n<26 -> W2r[k][n-16]; else 0
__global__ void k_prep_w2(const float* __restrict__ W2l, const float* __restrict__ W2r,
                          __hip_bfloat16* __restrict__ Wt2) {
    int idx = blockIdx.x * 256 + threadIdx.x;  // 32*256
    int n = idx >> 8, k = idx & 255;
    float v = 0.f;
    if (n < OUT_C) v = W2l[k * OUT_C + n];
    else if (n >= 16 && n < 16 + OUT_C) v = W2r[k * OUT_C + (n - 16)];
    Wt2[idx] = __float2bfloat16(v);
}

// ---------- GEMM1: [Ab | Bh] = Xb @ [W1l | W1r] (+b1 on Bh), 64x64 per wave ----------
__global__ __launch_bounds__(256) void k_gemm1(
        const __hip_bfloat16* __restrict__ Xb, const __hip_bfloat16* __restrict__ Wt,
        const float* __restrict__ b1,
        __hip_bfloat16* __restrict__ Ab, __hip_bfloat16* __restrict__ Bh) {
    int wave = threadIdx.x >> 6, lane = threadIdx.x & 63;
    int r = lane & 15, quad = lane >> 4;
    int m_base = blockIdx.x * 64;
    int n_base = blockIdx.y * 256 + wave * 64;

    const bf16x8* ap[4];
    const bf16x8* bp[4];
#pragma unroll
    for (int i = 0; i < 4; ++i) {
        int row = m_base + 16 * i + r;
        if (row > N_NODES - 1) row = N_NODES - 1;
        ap[i] = (const bf16x8*)(Xb + (size_t)row * IN_C + quad * 8);
        bp[i] = (const bf16x8*)(Wt + (size_t)(n_base + 16 * i + r) * IN_C + quad * 8);
    }
    f32x4 acc[4][4];
#pragma unroll
    for (int i = 0; i < 4; ++i)
#pragma unroll
        for (int j = 0; j < 4; ++j) acc[i][j] = f32x4{0.f, 0.f, 0.f, 0.f};

#pragma unroll
    for (int kk = 0; kk < IN_C / 32; ++kk) {
        bf16x8 a[4], b[4];
#pragma unroll
        for (int i = 0; i < 4; ++i) a[i] = ap[i][kk * 4];
#pragma unroll
        for (int j = 0; j < 4; ++j) b[j] = bp[j][kk * 4];
#pragma unroll
        for (int i = 0; i < 4; ++i)
#pragma unroll
            for (int j = 0; j < 4; ++j)
                acc[i][j] = __builtin_amdgcn_mfma_f32_16x16x32_bf16(a[i], b[j], acc[i][j], 0, 0, 0);
    }

    bool left = (n_base < HID_C);  // block-uniform
#pragma unroll
    for (int j = 0; j < 4; ++j) {
        int col = n_base + 16 * j + r;
        float bias = left ? 0.f : b1[col - HID_C];
#pragma unroll
        for (int i = 0; i < 4; ++i) {
#pragma unroll
            for (int ii = 0; ii < 4; ++ii) {
                int row = m_base + 16 * i + quad * 4 + ii;
                if (row < N_NODES) {
                    float v = acc[i][j][ii];
                    if (left) Ab[(size_t)row * HID_C + col] = __float2bfloat16(v);
                    else      Bh[(size_t)row * HID_C + (col - HID_C)] = __float2bfloat16(v + bias);
                }
            }
        }
    }
}

// ---------- layer1 aggregation + relu: one wave per node, bf16x8 per lane ----------
__global__ __launch_bounds__(256) void k_agg1(
        const __hip_bfloat16* __restrict__ Ab, const int* __restrict__ row_start,
        const int* __restrict__ cnt, const int* __restrict__ csr_src,
        __hip_bfloat16* __restrict__ Bh) {
    int wave = threadIdx.x >> 6, lane = threadIdx.x & 63;
    int nid = blockIdx.x * 4 + wave;          // grid 12500 -> exact
    int half = lane >> 5;
    int c8 = (lane & 31) * 8;
    int rs = row_start[nid];
    int n = cnt[nid];

    float s0[8], s1[8];
#pragma unroll
    for (int j = 0; j < 8; ++j) { s0[j] = 0.f; s1[j] = 0.f; }

    int e = half;
    for (; e + 2 < n; e += 4) {
        int i0 = csr_src[rs + e];
        int i1 = csr_src[rs + e + 2];
        bf16x8 v0 = *(const bf16x8*)(Ab + (size_t)i0 * HID_C + c8);
        bf16x8 v1 = *(const bf16x8*)(Ab + (size_t)i1 * HID_C + c8);
#pragma unroll
        for (int j = 0; j < 8; ++j) { s0[j] += b2f(v0[j]); s1[j] += b2f(v1[j]); }
    }
    if (e < n) {
        int i0 = csr_src[rs + e];
        bf16x8 v0 = *(const bf16x8*)(Ab + (size_t)i0 * HID_C + c8);
#pragma unroll
        for (int j = 0; j < 8; ++j) s0[j] += b2f(v0[j]);
    }
#pragma unroll
    for (int j = 0; j < 8; ++j) s0[j] += s1[j];
#pragma unroll
    for (int j = 0; j < 8; ++j) s0[j] += __shfl_down(s0[j], 32, 64);

    if (half == 0) {
        float inv = 1.f / fmaxf((float)n, 1.f);
        bf16x8 b = *(const bf16x8*)(Bh + (size_t)nid * HID_C + c8);
        bf16x8 o;
#pragma unroll
        for (int j = 0; j < 8; ++j) {
            float h = s0[j] * inv + b2f(b[j]);
            o[j] = f2b(fmaxf(h, 0.f));
        }
        *(bf16x8*)(Bh + (size_t)nid * HID_C + c8) = o;
    }
}

// ---------- GEMM2 (MFMA): CD[row][0..15]=h@W2l ; CD[row][16..31]=h@W2r+b2 ----------
__global__ __launch_bounds__(256) void k_gemm2(
        const __hip_bfloat16* __restrict__ h, const __hip_bfloat16* __restrict__ Wt2,
        const float* __restrict__ b2, float* __restrict__ CD) {
    int wave = threadIdx.x >> 6, lane = threadIdx.x & 63;
    int r = lane & 15, quad = lane >> 4;
    int m0 = blockIdx.x * 64 + wave * 16;     // grid 782
    int row_a = m0 + r;
    if (row_a > N_NODES - 1) row_a = N_NODES - 1;
    const bf16x8* ap  = (const bf16x8*)(h   + (size_t)row_a * HID_C + quad * 8);
    const bf16x8* bp0 = (const bf16x8*)(Wt2 + (size_t)r * HID_C + quad * 8);
    const bf16x8* bp1 = (const bf16x8*)(Wt2 + (size_t)(16 + r) * HID_C + quad * 8);
    f32x4 acc0 = {0.f, 0.f, 0.f, 0.f}, acc1 = {0.f, 0.f, 0.f, 0.f};
#pragma unroll
    for (int kk = 0; kk < HID_C / 32; ++kk) {
        bf16x8 a  = ap[kk * 4];
        bf16x8 b0 = bp0[kk * 4];
        bf16x8 b1v = bp1[kk * 4];
        acc0 = __builtin_amdgcn_mfma_f32_16x16x32_bf16(a, b0, acc0, 0, 0, 0);
        acc1 = __builtin_amdgcn_mfma_f32_16x16x32_bf16(a, b1v, acc1, 0, 0, 0);
    }
    float bias = (r < OUT_C) ? b2[r] : 0.f;
#pragma unroll
    for (int ii = 0; ii < 4; ++ii) {
        int row = m0 + quad * 4 + ii;
        if (row < N_NODES) {
            CD[(size_t)row * CD_STRIDE + r]      = acc0[ii];
            CD[(size_t)row * CD_STRIDE + 16 + r] = acc1[ii] + bias;
        }
    }
}

// ---------- layer2 aggregation + log_softmax: one wave per node ----------
__global__ __launch_bounds__(256) void k_agg2(
        const float* __restrict__ CD, const int* __restrict__ row_start,
        const int* __restrict__ cnt, const int* __restrict__ csr_src,
        float* __restrict__ out) {
    int wave = threadIdx.x >> 6, lane = threadIdx.x & 63;
    int nid = blockIdx.x * 4 + wave;          // grid 12500
    int rs = row_start[nid];
    int n = cnt[nid];
    float s[10];
#pragma unroll
    for (int j = 0; j < 10; ++j) s[j] = 0.f;
    for (int e = lane; e < n; e += 64) {
        const float* cr = CD + (size_t)csr_src[rs + e] * CD_STRIDE;
        f32x4 v0 = *(const f32x4*)cr;
        f32x4 v1 = *(const f32x4*)(cr + 4);
        f32x4 v2 = *(const f32x4*)(cr + 8);   // cols 8..11 (10,11 are zero)
#pragma unroll
        for (int j = 0; j < 4; ++j) { s[j] += v0[j]; s[4 + j] += v1[j]; }
        s[8] += v2[0]; s[9] += v2[1];
    }
#pragma unroll
    for (int j = 0; j < 10; ++j)
#pragma unroll
        for (int off = 32; off > 0; off >>= 1)
            s[j] += __shfl_down(s[j], off, 64);
    if (lane == 0) {
        float inv = 1.f / fmaxf((float)n, 1.f);
        float z[10], mx = -1e30f;
#pragma unroll
        for (int j = 0; j < 10; ++j) {
            z[j] = s[j] * inv + CD[(size_t)nid * CD_STRIDE + 16 + j];
            mx = fmaxf(mx, z[j]);
        }
        float se = 0.f;
#pragma unroll
        for (int j = 0; j < 10; ++j) se += expf(z[j] - mx);
        float lse = logf(se) + mx;
#pragma unroll
        for (int j = 0; j < 10; ++j) out[(size_t)nid * OUT_C + j] = z[j] - lse;
    }
}

extern "C" void kernel_launch(void* const* d_in, const int* in_sizes, int n_in,
                              void* d_out, int out_size, void* d_ws, size_t ws_size,
                              hipStream_t stream) {
    const float* x   = (const float*)d_in[0];
    const int*   ei  = (const int*)d_in[1];
    const float* W1l = (const float*)d_in[2];
    const float* W1r = (const float*)d_in[3];
    const float* b1  = (const float*)d_in[4];
    const float* W2l = (const float*)d_in[5];
    const float* W2r = (const float*)d_in[6];
    const float* b2  = (const float*)d_in[7];
    float* out = (float*)d_out;
    const int* src = ei;
    const int* dst = ei + N_EDGES;

    char* w = (char*)d_ws;
    size_t off = 0;
    auto alloc = [&](size_t bytes) -> void* {
        void* p = w + off;
        off = (off + bytes + 255) & ~(size_t)255;
        return p;
    };
    __hip_bfloat16* Xb  = (__hip_bfloat16*)alloc((size_t)N_NODES * IN_C * 2);
    __hip_bfloat16* Wt  = (__hip_bfloat16*)alloc((size_t)2 * HID_C * IN_C * 2);
    __hip_bfloat16* Wt2 = (__hip_bfloat16*)alloc((size_t)32 * HID_C * 2);
    __hip_bfloat16* Ab  = (__hip_bfloat16*)alloc((size_t)N_NODES * HID_C * 2);
    __hip_bfloat16* Bh  = (__hip_bfloat16*)alloc((size_t)N_NODES * HID_C * 2);
    float* CD = (float*)alloc((size_t)N_NODES * CD_STRIDE * 4);
    int* cnt       = (int*)alloc((size_t)N_NODES * 4);
    int* row_start = (int*)alloc((size_t)N_NODES * 4);
    int* cursor    = (int*)alloc((size_t)N_NODES * 4);
    int* blocksum  = (int*)alloc(256 * 4);
    int* blockoff  = (int*)alloc(256 * 4);
    int* csr_src   = (int*)alloc((size_t)N_EDGES * 4);

    hipMemsetAsync(cnt, 0, (size_t)N_NODES * 4, stream);

    k_count<<<(N_EDGES / 4 + 255) / 256, 256, 0, stream>>>(dst, cnt);
    k_scan1<<<SCAN_BLOCKS, 256, 0, stream>>>(cnt, row_start, blocksum);
    k_scan2<<<1, 256, 0, stream>>>(blocksum, blockoff);
    k_scan3<<<SCAN_BLOCKS, 256, 0, stream>>>(row_start, blockoff, cursor);
    k_fill<<<(N_EDGES / 4 + 255) / 256, 256, 0, stream>>>(src, dst, cursor, csr_src);

    k_cvt_x<<<(N_NODES * IN_C / 4) / 256, 256, 0, stream>>>((const float4*)x, (short4*)Xb);
    k_prep_w<<<512, 256, 0, stream>>>(W1l, W1r, Wt);
    k_prep_w2<<<32, 256, 0, stream>>>(W2l, W2r, Wt2);

    k_gemm1<<<dim3((N_NODES + 63) / 64, 2), 256, 0, stream>>>(Xb, Wt, b1, Ab, Bh);
    k_agg1<<<N_NODES / 4, 256, 0, stream>>>(Ab, row_start, cnt, csr_src, Bh);
    k_gemm2<<<(N_NODES + 63) / 64, 256, 0, stream>>>(Bh, Wt2, b2, CD);
    k_agg2<<<N_NODES / 4, 256, 0, stream>>>(CD, row_start, cnt, csr_src, out);
}

// Round 3
// 466.689 us; speedup vs baseline: 2.3105x; 1.1589x over previous
//
#include <hip/hip_runtime.h>
#include <hip/hip_bf16.h>

#define N_NODES 50000
#define N_EDGES 1600000
#define IN_C 256
#define HID_C 256
#define OUT_C 10
#define CD_STRIDE 32
#define SLOT_CAP 128   // max degree; Poisson(32) tail P(>128) ~ 1e-31

typedef short bf16x8 __attribute__((ext_vector_type(8)));
typedef float f32x4 __attribute__((ext_vector_type(4)));

static __device__ __forceinline__ float b2f(short v) {
    unsigned u = (unsigned)(unsigned short)v << 16;
    return __builtin_bit_cast(float, u);
}
static __device__ __forceinline__ short f2b(float f) {
    __hip_bfloat16 h = __float2bfloat16(f);
    return __builtin_bit_cast(short, h);
}

// ---------- fused bucket build: count + fill in one pass ----------
__global__ __launch_bounds__(256) void k_build(const int* __restrict__ src,
                                               const int* __restrict__ dst,
                                               int* __restrict__ cnt,
                                               int* __restrict__ slots) {
    int t = blockIdx.x * 256 + threadIdx.x;
    if (t < N_EDGES / 4) {
        int4 s = ((const int4*)src)[t];
        int4 d = ((const int4*)dst)[t];
        // issue all 4 atomics first (independent -> overlap latency)
        int p0 = atomicAdd(&cnt[d.x], 1);
        int p1 = atomicAdd(&cnt[d.y], 1);
        int p2 = atomicAdd(&cnt[d.z], 1);
        int p3 = atomicAdd(&cnt[d.w], 1);
        if (p0 < SLOT_CAP) slots[d.x * SLOT_CAP + p0] = s.x;
        if (p1 < SLOT_CAP) slots[d.y * SLOT_CAP + p1] = s.y;
        if (p2 < SLOT_CAP) slots[d.z * SLOT_CAP + p2] = s.z;
        if (p3 < SLOT_CAP) slots[d.w * SLOT_CAP + p3] = s.w;
    }
}

// ---------- prep ----------
__global__ void k_cvt_x(const float4* __restrict__ x, short4* __restrict__ xb) {
    int i = blockIdx.x * 256 + threadIdx.x;   // N_NODES*IN_C/4 threads exactly
    float4 v = x[i];
    short4 o = { f2b(v.x), f2b(v.y), f2b(v.z), f2b(v.w) };
    xb[i] = o;
}

// Wt[n][k], n in [0,512): n<256 -> W1l[k][n], else W1r[k][n-256]
__global__ void k_prep_w(const float* __restrict__ W1l, const float* __restrict__ W1r,
                         __hip_bfloat16* __restrict__ Wt) {
    int idx = blockIdx.x * 256 + threadIdx.x;  // 512*256
    int n = idx >> 8, k = idx & 255;
    float v = (n < HID_C) ? W1l[k * HID_C + n] : W1r[k * HID_C + (n - HID_C)];
    Wt[idx] = __float2bfloat16(v);
}

// Wt2[n][k], n in [0,32): n<10 -> W2l[k][n]; 16<=n<26 -> W2r[k][n-16]; else 0
__global__ void k_prep_w2(const float* __restrict__ W2l, const float* __restrict__ W2r,
                          __hip_bfloat16* __restrict__ Wt2) {
    int idx = blockIdx.x * 256 + threadIdx.x;  // 32*256
    int n = idx >> 8, k = idx & 255;
    float v = 0.f;
    if (n < OUT_C) v = W2l[k * OUT_C + n];
    else if (n >= 16 && n < 16 + OUT_C) v = W2r[k * OUT_C + (n - 16)];
    Wt2[idx] = __float2bfloat16(v);
}

// ---------- GEMM1: [Ab | Bh] = Xb @ [W1l | W1r] (+b1 on Bh), 64x64 per wave ----------
__global__ __launch_bounds__(256) void k_gemm1(
        const __hip_bfloat16* __restrict__ Xb, const __hip_bfloat16* __restrict__ Wt,
        const float* __restrict__ b1,
        __hip_bfloat16* __restrict__ Ab, __hip_bfloat16* __restrict__ Bh) {
    int wave = threadIdx.x >> 6, lane = threadIdx.x & 63;
    int r = lane & 15, quad = lane >> 4;
    int m_base = blockIdx.x * 64;
    int n_base = blockIdx.y * 256 + wave * 64;

    const bf16x8* ap[4];
    const bf16x8* bp[4];
#pragma unroll
    for (int i = 0; i < 4; ++i) {
        int row = m_base + 16 * i + r;
        if (row > N_NODES - 1) row = N_NODES - 1;
        ap[i] = (const bf16x8*)(Xb + (size_t)row * IN_C + quad * 8);
        bp[i] = (const bf16x8*)(Wt + (size_t)(n_base + 16 * i + r) * IN_C + quad * 8);
    }
    f32x4 acc[4][4];
#pragma unroll
    for (int i = 0; i < 4; ++i)
#pragma unroll
        for (int j = 0; j < 4; ++j) acc[i][j] = f32x4{0.f, 0.f, 0.f, 0.f};

#pragma unroll
    for (int kk = 0; kk < IN_C / 32; ++kk) {
        bf16x8 a[4], b[4];
#pragma unroll
        for (int i = 0; i < 4; ++i) a[i] = ap[i][kk * 4];
#pragma unroll
        for (int j = 0; j < 4; ++j) b[j] = bp[j][kk * 4];
#pragma unroll
        for (int i = 0; i < 4; ++i)
#pragma unroll
            for (int j = 0; j < 4; ++j)
                acc[i][j] = __builtin_amdgcn_mfma_f32_16x16x32_bf16(a[i], b[j], acc[i][j], 0, 0, 0);
    }

    bool left = (n_base < HID_C);  // block-uniform
#pragma unroll
    for (int j = 0; j < 4; ++j) {
        int col = n_base + 16 * j + r;
        float bias = left ? 0.f : b1[col - HID_C];
#pragma unroll
        for (int i = 0; i < 4; ++i) {
#pragma unroll
            for (int ii = 0; ii < 4; ++ii) {
                int row = m_base + 16 * i + quad * 4 + ii;
                if (row < N_NODES) {
                    float v = acc[i][j][ii];
                    if (left) Ab[(size_t)row * HID_C + col] = __float2bfloat16(v);
                    else      Bh[(size_t)row * HID_C + (col - HID_C)] = __float2bfloat16(v + bias);
                }
            }
        }
    }
}

// ---------- layer1 aggregation + relu: one wave per node, bf16x8 per lane ----------
__global__ __launch_bounds__(256) void k_agg1(
        const __hip_bfloat16* __restrict__ Ab, const int* __restrict__ cnt,
        const int* __restrict__ slots, __hip_bfloat16* __restrict__ Bh) {
    int wave = threadIdx.x >> 6, lane = threadIdx.x & 63;
    int nid = blockIdx.x * 4 + wave;          // grid 12500 -> exact
    int half = lane >> 5;
    int c8 = (lane & 31) * 8;
    const int* row = slots + nid * SLOT_CAP;
    int n = cnt[nid];
    if (n > SLOT_CAP) n = SLOT_CAP;

    float s0[8], s1[8];
#pragma unroll
    for (int j = 0; j < 8; ++j) { s0[j] = 0.f; s1[j] = 0.f; }

    int e = half;
    for (; e + 2 < n; e += 4) {
        int i0 = row[e];
        int i1 = row[e + 2];
        bf16x8 v0 = *(const bf16x8*)(Ab + (size_t)i0 * HID_C + c8);
        bf16x8 v1 = *(const bf16x8*)(Ab + (size_t)i1 * HID_C + c8);
#pragma unroll
        for (int j = 0; j < 8; ++j) { s0[j] += b2f(v0[j]); s1[j] += b2f(v1[j]); }
    }
    if (e < n) {
        int i0 = row[e];
        bf16x8 v0 = *(const bf16x8*)(Ab + (size_t)i0 * HID_C + c8);
#pragma unroll
        for (int j = 0; j < 8; ++j) s0[j] += b2f(v0[j]);
    }
#pragma unroll
    for (int j = 0; j < 8; ++j) s0[j] += s1[j];
#pragma unroll
    for (int j = 0; j < 8; ++j) s0[j] += __shfl_down(s0[j], 32, 64);

    if (half == 0) {
        float inv = 1.f / fmaxf((float)n, 1.f);
        bf16x8 b = *(const bf16x8*)(Bh + (size_t)nid * HID_C + c8);
        bf16x8 o;
#pragma unroll
        for (int j = 0; j < 8; ++j) {
            float h = s0[j] * inv + b2f(b[j]);
            o[j] = f2b(fmaxf(h, 0.f));
        }
        *(bf16x8*)(Bh + (size_t)nid * HID_C + c8) = o;
    }
}

// ---------- GEMM2 (MFMA): CD[row][0..15]=h@W2l ; CD[row][16..31]=h@W2r+b2 ----------
__global__ __launch_bounds__(256) void k_gemm2(
        const __hip_bfloat16* __restrict__ h, const __hip_bfloat16* __restrict__ Wt2,
        const float* __restrict__ b2, float* __restrict__ CD) {
    int wave = threadIdx.x >> 6, lane = threadIdx.x & 63;
    int r = lane & 15, quad = lane >> 4;
    int m0 = blockIdx.x * 64 + wave * 16;     // grid 782
    int row_a = m0 + r;
    if (row_a > N_NODES - 1) row_a = N_NODES - 1;
    const bf16x8* ap  = (const bf16x8*)(h   + (size_t)row_a * HID_C + quad * 8);
    const bf16x8* bp0 = (const bf16x8*)(Wt2 + (size_t)r * HID_C + quad * 8);
    const bf16x8* bp1 = (const bf16x8*)(Wt2 + (size_t)(16 + r) * HID_C + quad * 8);
    f32x4 acc0 = {0.f, 0.f, 0.f, 0.f}, acc1 = {0.f, 0.f, 0.f, 0.f};
#pragma unroll
    for (int kk = 0; kk < HID_C / 32; ++kk) {
        bf16x8 a  = ap[kk * 4];
        bf16x8 b0 = bp0[kk * 4];
        bf16x8 b1v = bp1[kk * 4];
        acc0 = __builtin_amdgcn_mfma_f32_16x16x32_bf16(a, b0, acc0, 0, 0, 0);
        acc1 = __builtin_amdgcn_mfma_f32_16x16x32_bf16(a, b1v, acc1, 0, 0, 0);
    }
    float bias = (r < OUT_C) ? b2[r] : 0.f;
#pragma unroll
    for (int ii = 0; ii < 4; ++ii) {
        int row = m0 + quad * 4 + ii;
        if (row < N_NODES) {
            CD[(size_t)row * CD_STRIDE + r]      = acc0[ii];
            CD[(size_t)row * CD_STRIDE + 16 + r] = acc1[ii] + bias;
        }
    }
}

// ---------- layer2 aggregation + log_softmax: one wave per node ----------
__global__ __launch_bounds__(256) void k_agg2(
        const float* __restrict__ CD, const int* __restrict__ cnt,
        const int* __restrict__ slots, float* __restrict__ out) {
    int wave = threadIdx.x >> 6, lane = threadIdx.x & 63;
    int nid = blockIdx.x * 4 + wave;          // grid 12500
    const int* row = slots + nid * SLOT_CAP;
    int n = cnt[nid];
    if (n > SLOT_CAP) n = SLOT_CAP;
    float s[10];
#pragma unroll
    for (int j = 0; j < 10; ++j) s[j] = 0.f;
    for (int e = lane; e < n; e += 64) {
        const float* cr = CD + (size_t)row[e] * CD_STRIDE;
        f32x4 v0 = *(const f32x4*)cr;
        f32x4 v1 = *(const f32x4*)(cr + 4);
        f32x4 v2 = *(const f32x4*)(cr + 8);   // cols 8..11 (10,11 are zero)
#pragma unroll
        for (int j = 0; j < 4; ++j) { s[j] += v0[j]; s[4 + j] += v1[j]; }
        s[8] += v2[0]; s[9] += v2[1];
    }
#pragma unroll
    for (int j = 0; j < 10; ++j)
#pragma unroll
        for (int off = 32; off > 0; off >>= 1)
            s[j] += __shfl_down(s[j], off, 64);
    if (lane == 0) {
        float inv = 1.f / fmaxf((float)n, 1.f);
        float z[10], mx = -1e30f;
#pragma unroll
        for (int j = 0; j < 10; ++j) {
            z[j] = s[j] * inv + CD[(size_t)nid * CD_STRIDE + 16 + j];
            mx = fmaxf(mx, z[j]);
        }
        float se = 0.f;
#pragma unroll
        for (int j = 0; j < 10; ++j) se += expf(z[j] - mx);
        float lse = logf(se) + mx;
#pragma unroll
        for (int j = 0; j < 10; ++j) out[(size_t)nid * OUT_C + j] = z[j] - lse;
    }
}

extern "C" void kernel_launch(void* const* d_in, const int* in_sizes, int n_in,
                              void* d_out, int out_size, void* d_ws, size_t ws_size,
                              hipStream_t stream) {
    const float* x   = (const float*)d_in[0];
    const int*   ei  = (const int*)d_in[1];
    const float* W1l = (const float*)d_in[2];
    const float* W1r = (const float*)d_in[3];
    const float* b1  = (const float*)d_in[4];
    const float* W2l = (const float*)d_in[5];
    const float* W2r = (const float*)d_in[6];
    const float* b2  = (const float*)d_in[7];
    float* out = (float*)d_out;
    const int* src = ei;
    const int* dst = ei + N_EDGES;

    char* w = (char*)d_ws;
    size_t off = 0;
    auto alloc = [&](size_t bytes) -> void* {
        void* p = w + off;
        off = (off + bytes + 255) & ~(size_t)255;
        return p;
    };
    __hip_bfloat16* Xb  = (__hip_bfloat16*)alloc((size_t)N_NODES * IN_C * 2);
    __hip_bfloat16* Wt  = (__hip_bfloat16*)alloc((size_t)2 * HID_C * IN_C * 2);
    __hip_bfloat16* Wt2 = (__hip_bfloat16*)alloc((size_t)32 * HID_C * 2);
    __hip_bfloat16* Ab  = (__hip_bfloat16*)alloc((size_t)N_NODES * HID_C * 2);
    __hip_bfloat16* Bh  = (__hip_bfloat16*)alloc((size_t)N_NODES * HID_C * 2);
    float* CD = (float*)alloc((size_t)N_NODES * CD_STRIDE * 4);
    int* cnt   = (int*)alloc((size_t)N_NODES * 4);
    int* slots = (int*)alloc((size_t)N_NODES * SLOT_CAP * 4);

    hipMemsetAsync(cnt, 0, (size_t)N_NODES * 4, stream);

    k_build<<<(N_EDGES / 4 + 255) / 256, 256, 0, stream>>>(src, dst, cnt, slots);

    k_cvt_x<<<(N_NODES * IN_C / 4) / 256, 256, 0, stream>>>((const float4*)x, (short4*)Xb);
    k_prep_w<<<512, 256, 0, stream>>>(W1l, W1r, Wt);
    k_prep_w2<<<32, 256, 0, stream>>>(W2l, W2r, Wt2);

    k_gemm1<<<dim3((N_NODES + 63) / 64, 2), 256, 0, stream>>>(Xb, Wt, b1, Ab, Bh);
    k_agg1<<<N_NODES / 4, 256, 0, stream>>>(Ab, cnt, slots, Bh);
    k_gemm2<<<(N_NODES + 63) / 64, 256, 0, stream>>>(Bh, Wt2, b2, CD);
    k_agg2<<<N_NODES / 4, 256, 0, stream>>>(CD, cnt, slots, out);
}

// Round 4
// 376.995 us; speedup vs baseline: 2.8603x; 1.2379x over previous
//
#include <hip/hip_runtime.h>
#include <hip/hip_bf16.h>

#define N_NODES 50000
#define N_EDGES 1600000
#define IN_C 256
#define HID_C 256
#define OUT_C 10
#define CD_STRIDE 32
#define SLOT_CAP 96      // max degree; Poisson(32) max over 50K nodes ~60; 96 = 11 sigma
#define NBUCKET 196      // ceil(50000/256) dst-buckets of 256 nodes
#define EBUF_CAP 9216    // per-bucket edge capacity; mean 8163, sigma 90 -> +11.7 sigma

typedef short bf16x8 __attribute__((ext_vector_type(8)));
typedef float f32x4 __attribute__((ext_vector_type(4)));

static __device__ __forceinline__ float b2f(short v) {
    unsigned u = (unsigned)(unsigned short)v << 16;
    return __builtin_bit_cast(float, u);
}
static __device__ __forceinline__ short f2b(float f) {
    __hip_bfloat16 h = __float2bfloat16(f);
    return __builtin_bit_cast(short, h);
}

// ---------- phase A: partition edges into 196 dst-buckets (packed 4B records) ----------
__global__ __launch_bounds__(256) void k_part(const int* __restrict__ src,
                                              const int* __restrict__ dst,
                                              int* __restrict__ g_cursor,
                                              int* __restrict__ ebuf) {
    __shared__ int hist[NBUCKET];
    __shared__ int base[NBUCKET];
    __shared__ int pos[NBUCKET];
    int tid = threadIdx.x;
    if (tid < NBUCKET) { hist[tid] = 0; pos[tid] = 0; }
    __syncthreads();

    int4 s[2], d[2];
    bool valid[2];
#pragma unroll
    for (int q = 0; q < 2; ++q) {
        int idx = blockIdx.x * 512 + q * 256 + tid;    // int4 index, 4 edges each
        valid[q] = (idx < N_EDGES / 4);
        if (valid[q]) {
            s[q] = ((const int4*)src)[idx];
            d[q] = ((const int4*)dst)[idx];
        }
    }
#pragma unroll
    for (int q = 0; q < 2; ++q) {
        if (valid[q]) {
            atomicAdd(&hist[d[q].x >> 8], 1);
            atomicAdd(&hist[d[q].y >> 8], 1);
            atomicAdd(&hist[d[q].z >> 8], 1);
            atomicAdd(&hist[d[q].w >> 8], 1);
        }
    }
    __syncthreads();
    if (tid < NBUCKET && hist[tid] > 0)
        base[tid] = atomicAdd(&g_cursor[tid], hist[tid]);
    __syncthreads();
#pragma unroll
    for (int q = 0; q < 2; ++q) {
        if (valid[q]) {
            int ss[4] = { s[q].x, s[q].y, s[q].z, s[q].w };
            int dd[4] = { d[q].x, d[q].y, d[q].z, d[q].w };
#pragma unroll
            for (int e = 0; e < 4; ++e) {
                int b = dd[e] >> 8;
                int p = base[b] + atomicAdd(&pos[b], 1);
                if (p < EBUF_CAP)
                    ebuf[b * EBUF_CAP + p] = ss[e] | ((dd[e] & 255) << 16);
            }
        }
    }
}

// ---------- phase B: one block per bucket, LDS counters, L2-local slot writes ----------
__global__ __launch_bounds__(256) void k_bucket(const int* __restrict__ ebuf,
                                                const int* __restrict__ g_cursor,
                                                int* __restrict__ cnt,
                                                int* __restrict__ slots) {
    __shared__ int lcnt[256];
    int b = blockIdx.x, tid = threadIdx.x;
    lcnt[tid] = 0;
    __syncthreads();
    int n_e = g_cursor[b];
    if (n_e > EBUF_CAP) n_e = EBUF_CAP;
    const int* eb = ebuf + b * EBUF_CAP;
    int n4 = n_e >> 2;
    for (int t = tid; t < n4; t += 256) {
        int4 v = ((const int4*)eb)[t];
        int vv[4] = { v.x, v.y, v.z, v.w };
#pragma unroll
        for (int e = 0; e < 4; ++e) {
            int dl = (vv[e] >> 16) & 255;
            int sv = vv[e] & 0xFFFF;
            int p = atomicAdd(&lcnt[dl], 1);
            if (p < SLOT_CAP) slots[(size_t)(b * 256 + dl) * SLOT_CAP + p] = sv;
        }
    }
    for (int t = (n4 << 2) + tid; t < n_e; t += 256) {
        int vv = eb[t];
        int dl = (vv >> 16) & 255;
        int sv = vv & 0xFFFF;
        int p = atomicAdd(&lcnt[dl], 1);
        if (p < SLOT_CAP) slots[(size_t)(b * 256 + dl) * SLOT_CAP + p] = sv;
    }
    __syncthreads();
    int nid = b * 256 + tid;
    if (nid < N_NODES) cnt[nid] = lcnt[tid];
}

// ---------- prep ----------
__global__ void k_cvt_x(const float4* __restrict__ x, short4* __restrict__ xb) {
    int i = blockIdx.x * 256 + threadIdx.x;   // N_NODES*IN_C/4 threads exactly
    float4 v = x[i];
    short4 o = { f2b(v.x), f2b(v.y), f2b(v.z), f2b(v.w) };
    xb[i] = o;
}

// Wt[n][k], n in [0,512): n<256 -> W1l[k][n], else W1r[k][n-256]
__global__ void k_prep_w(const float* __restrict__ W1l, const float* __restrict__ W1r,
                         __hip_bfloat16* __restrict__ Wt) {
    int idx = blockIdx.x * 256 + threadIdx.x;  // 512*256
    int n = idx >> 8, k = idx & 255;
    float v = (n < HID_C) ? W1l[k * HID_C + n] : W1r[k * HID_C + (n - HID_C)];
    Wt[idx] = __float2bfloat16(v);
}

// Wt2f rows 0..9 = W2l^T, rows 16..25 = W2r^T, fp32, stride 256
__global__ void k_prep_w2f(const float* __restrict__ W2l, const float* __restrict__ W2r,
                           float* __restrict__ Wt2f) {
    int idx = blockIdx.x * 256 + threadIdx.x;  // 20*256
    int r = idx >> 8, k = idx & 255;
    if (r < OUT_C) Wt2f[r * 256 + k] = W2l[k * OUT_C + r];
    else           Wt2f[(16 + r - OUT_C) * 256 + k] = W2r[k * OUT_C + (r - OUT_C)];
}

// ---------- GEMM1: [Ab | Bh] = Xb @ [W1l | W1r] (+b1 on Bh), 64x64 per wave ----------
__global__ __launch_bounds__(256) void k_gemm1(
        const __hip_bfloat16* __restrict__ Xb, const __hip_bfloat16* __restrict__ Wt,
        const float* __restrict__ b1,
        __hip_bfloat16* __restrict__ Ab, __hip_bfloat16* __restrict__ Bh) {
    int wave = threadIdx.x >> 6, lane = threadIdx.x & 63;
    int r = lane & 15, quad = lane >> 4;
    int m_base = blockIdx.x * 64;
    int n_base = blockIdx.y * 256 + wave * 64;

    const bf16x8* ap[4];
    const bf16x8* bp[4];
#pragma unroll
    for (int i = 0; i < 4; ++i) {
        int row = m_base + 16 * i + r;
        if (row > N_NODES - 1) row = N_NODES - 1;
        ap[i] = (const bf16x8*)(Xb + (size_t)row * IN_C + quad * 8);
        bp[i] = (const bf16x8*)(Wt + (size_t)(n_base + 16 * i + r) * IN_C + quad * 8);
    }
    f32x4 acc[4][4];
#pragma unroll
    for (int i = 0; i < 4; ++i)
#pragma unroll
        for (int j = 0; j < 4; ++j) acc[i][j] = f32x4{0.f, 0.f, 0.f, 0.f};

#pragma unroll
    for (int kk = 0; kk < IN_C / 32; ++kk) {
        bf16x8 a[4], b[4];
#pragma unroll
        for (int i = 0; i < 4; ++i) a[i] = ap[i][kk * 4];
#pragma unroll
        for (int j = 0; j < 4; ++j) b[j] = bp[j][kk * 4];
#pragma unroll
        for (int i = 0; i < 4; ++i)
#pragma unroll
            for (int j = 0; j < 4; ++j)
                acc[i][j] = __builtin_amdgcn_mfma_f32_16x16x32_bf16(a[i], b[j], acc[i][j], 0, 0, 0);
    }

    bool left = (n_base < HID_C);  // block-uniform
#pragma unroll
    for (int j = 0; j < 4; ++j) {
        int col = n_base + 16 * j + r;
        float bias = left ? 0.f : b1[col - HID_C];
#pragma unroll
        for (int i = 0; i < 4; ++i) {
#pragma unroll
            for (int ii = 0; ii < 4; ++ii) {
                int row = m_base + 16 * i + quad * 4 + ii;
                if (row < N_NODES) {
                    float v = acc[i][j][ii];
                    if (left) Ab[(size_t)row * HID_C + col] = __float2bfloat16(v);
                    else      Bh[(size_t)row * HID_C + (col - HID_C)] = __float2bfloat16(v + bias);
                }
            }
        }
    }
}

// ---------- fused: layer1 mean-agg + relu + GEMM2 epilogue -> CD ----------
// half0 lanes compute C = h@W2l (CD cols 0..9, cols 10,11 zeroed)
// half1 lanes compute D = h@W2r + b2 (CD cols 16..25)
__global__ __launch_bounds__(256) void k_agg1f(
        const __hip_bfloat16* __restrict__ Ab, const __hip_bfloat16* __restrict__ Bh,
        const int* __restrict__ cnt, const int* __restrict__ slots,
        const float* __restrict__ Wt2f, const float* __restrict__ b2,
        float* __restrict__ CD) {
    int wave = threadIdx.x >> 6, lane = threadIdx.x & 63;
    int nid = blockIdx.x * 4 + wave;          // grid 12500 -> exact
    int half = lane >> 5;
    int c8 = (lane & 31) * 8;
    const int* row = slots + (size_t)nid * SLOT_CAP;
    int n = cnt[nid];
    if (n > SLOT_CAP) n = SLOT_CAP;

    float s0[8], s1[8];
#pragma unroll
    for (int j = 0; j < 8; ++j) { s0[j] = 0.f; s1[j] = 0.f; }

    int e = half;
    for (; e + 2 < n; e += 4) {
        int i0 = row[e];
        int i1 = row[e + 2];
        bf16x8 v0 = *(const bf16x8*)(Ab + (size_t)i0 * HID_C + c8);
        bf16x8 v1 = *(const bf16x8*)(Ab + (size_t)i1 * HID_C + c8);
#pragma unroll
        for (int j = 0; j < 8; ++j) { s0[j] += b2f(v0[j]); s1[j] += b2f(v1[j]); }
    }
    if (e < n) {
        int i0 = row[e];
        bf16x8 v0 = *(const bf16x8*)(Ab + (size_t)i0 * HID_C + c8);
#pragma unroll
        for (int j = 0; j < 8; ++j) s0[j] += b2f(v0[j]);
    }
#pragma unroll
    for (int j = 0; j < 8; ++j) s0[j] += s1[j];
#pragma unroll
    for (int j = 0; j < 8; ++j) s0[j] += __shfl_down(s0[j], 32, 64);

    // h = relu(mean + Bh) computed on half0, broadcast to half1
    float h[8];
    float inv = 1.f / fmaxf((float)n, 1.f);
    if (half == 0) {
        bf16x8 bb = *(const bf16x8*)(Bh + (size_t)nid * HID_C + c8);
#pragma unroll
        for (int j = 0; j < 8; ++j)
            h[j] = fmaxf(s0[j] * inv + b2f(bb[j]), 0.f);
    }
#pragma unroll
    for (int j = 0; j < 8; ++j) h[j] = __shfl(h[j], lane & 31, 64);

    // 10 dot products with W2 (fp32), reduce over 32 lanes of this half
    const float* wbase = Wt2f + (half ? 16 * 256 : 0);
    float acc[10];
#pragma unroll
    for (int j = 0; j < 10; ++j) {
        f32x4 w0 = *(const f32x4*)(wbase + j * 256 + c8);
        f32x4 w1 = *(const f32x4*)(wbase + j * 256 + c8 + 4);
        float a = h[0] * w0[0] + h[1] * w0[1] + h[2] * w0[2] + h[3] * w0[3]
                + h[4] * w1[0] + h[5] * w1[1] + h[6] * w1[2] + h[7] * w1[3];
#pragma unroll
        for (int off = 16; off > 0; off >>= 1)
            a += __shfl_down(a, off, 32);
        acc[j] = a;
    }
    if ((lane & 31) == 0) {
        float* o = CD + (size_t)nid * CD_STRIDE + half * 16;
        if (half == 0) {
#pragma unroll
            for (int j = 0; j < 10; ++j) o[j] = acc[j];
            o[10] = 0.f; o[11] = 0.f;
        } else {
#pragma unroll
            for (int j = 0; j < 10; ++j) o[j] = acc[j] + b2[j];
        }
    }
}

// ---------- layer2 aggregation + log_softmax: one wave per node ----------
__global__ __launch_bounds__(256) void k_agg2(
        const float* __restrict__ CD, const int* __restrict__ cnt,
        const int* __restrict__ slots, float* __restrict__ out) {
    int wave = threadIdx.x >> 6, lane = threadIdx.x & 63;
    int nid = blockIdx.x * 4 + wave;          // grid 12500
    const int* row = slots + (size_t)nid * SLOT_CAP;
    int n = cnt[nid];
    if (n > SLOT_CAP) n = SLOT_CAP;
    float s[10];
#pragma unroll
    for (int j = 0; j < 10; ++j) s[j] = 0.f;
    for (int e = lane; e < n; e += 64) {
        const float* cr = CD + (size_t)row[e] * CD_STRIDE;
        f32x4 v0 = *(const f32x4*)cr;
        f32x4 v1 = *(const f32x4*)(cr + 4);
        f32x4 v2 = *(const f32x4*)(cr + 8);   // cols 8..11 (10,11 zeroed)
#pragma unroll
        for (int j = 0; j < 4; ++j) { s[j] += v0[j]; s[4 + j] += v1[j]; }
        s[8] += v2[0]; s[9] += v2[1];
    }
#pragma unroll
    for (int j = 0; j < 10; ++j)
#pragma unroll
        for (int off = 32; off > 0; off >>= 1)
            s[j] += __shfl_down(s[j], off, 64);
    if (lane == 0) {
        float inv = 1.f / fmaxf((float)n, 1.f);
        float z[10], mx = -1e30f;
#pragma unroll
        for (int j = 0; j < 10; ++j) {
            z[j] = s[j] * inv + CD[(size_t)nid * CD_STRIDE + 16 + j];
            mx = fmaxf(mx, z[j]);
        }
        float se = 0.f;
#pragma unroll
        for (int j = 0; j < 10; ++j) se += expf(z[j] - mx);
        float lse = logf(se) + mx;
#pragma unroll
        for (int j = 0; j < 10; ++j) out[(size_t)nid * OUT_C + j] = z[j] - lse;
    }
}

extern "C" void kernel_launch(void* const* d_in, const int* in_sizes, int n_in,
                              void* d_out, int out_size, void* d_ws, size_t ws_size,
                              hipStream_t stream) {
    const float* x   = (const float*)d_in[0];
    const int*   ei  = (const int*)d_in[1];
    const float* W1l = (const float*)d_in[2];
    const float* W1r = (const float*)d_in[3];
    const float* b1  = (const float*)d_in[4];
    const float* W2l = (const float*)d_in[5];
    const float* W2r = (const float*)d_in[6];
    const float* b2  = (const float*)d_in[7];
    float* out = (float*)d_out;
    const int* src = ei;
    const int* dst = ei + N_EDGES;

    char* w = (char*)d_ws;
    size_t off = 0;
    auto alloc = [&](size_t bytes) -> void* {
        void* p = w + off;
        off = (off + bytes + 255) & ~(size_t)255;
        return p;
    };
    __hip_bfloat16* Xb   = (__hip_bfloat16*)alloc((size_t)N_NODES * IN_C * 2);
    __hip_bfloat16* Wt   = (__hip_bfloat16*)alloc((size_t)2 * HID_C * IN_C * 2);
    float*          Wt2f = (float*)alloc((size_t)32 * 256 * 4);
    __hip_bfloat16* Ab   = (__hip_bfloat16*)alloc((size_t)N_NODES * HID_C * 2);
    __hip_bfloat16* Bh   = (__hip_bfloat16*)alloc((size_t)N_NODES * HID_C * 2);
    float* CD = (float*)alloc((size_t)N_NODES * CD_STRIDE * 4);
    int* cnt      = (int*)alloc((size_t)N_NODES * 4);
    int* slots    = (int*)alloc((size_t)N_NODES * SLOT_CAP * 4);
    int* g_cursor = (int*)alloc((size_t)NBUCKET * 4);
    int* ebuf     = (int*)alloc((size_t)NBUCKET * EBUF_CAP * 4);

    hipMemsetAsync(g_cursor, 0, (size_t)NBUCKET * 4, stream);

    k_part<<<(N_EDGES / 4 + 511) / 512, 256, 0, stream>>>(src, dst, g_cursor, ebuf);
    k_bucket<<<NBUCKET, 256, 0, stream>>>(ebuf, g_cursor, cnt, slots);

    k_cvt_x<<<(N_NODES * IN_C / 4) / 256, 256, 0, stream>>>((const float4*)x, (short4*)Xb);
    k_prep_w<<<512, 256, 0, stream>>>(W1l, W1r, Wt);
    k_prep_w2f<<<20, 256, 0, stream>>>(W2l, W2r, Wt2f);

    k_gemm1<<<dim3((N_NODES + 63) / 64, 2), 256, 0, stream>>>(Xb, Wt, b1, Ab, Bh);
    k_agg1f<<<N_NODES / 4, 256, 0, stream>>>(Ab, Bh, cnt, slots, Wt2f, b2, CD);
    k_agg2<<<N_NODES / 4, 256, 0, stream>>>(CD, cnt, slots, out);
}

// Round 5
// 347.756 us; speedup vs baseline: 3.1008x; 1.0841x over previous
//
#include <hip/hip_runtime.h>
#include <hip/hip_bf16.h>

#define N_NODES 50000
#define N_EDGES 1600000
#define IN_C 256
#define HID_C 256
#define OUT_C 10
#define CD_STRIDE 32
#define SLOT_CAP 96      // max degree; Poisson(32) max over 50K nodes ~60; 96 = 11 sigma
#define NBUCKET 196      // ceil(50000/256) dst-buckets of 256 nodes
#define EBUF_CAP 9216    // per-bucket edge capacity; mean 8163, sigma 90 -> +11.7 sigma

typedef short bf16x8 __attribute__((ext_vector_type(8)));
typedef float f32x4 __attribute__((ext_vector_type(4)));

static __device__ __forceinline__ float b2f(short v) {
    unsigned u = (unsigned)(unsigned short)v << 16;
    return __builtin_bit_cast(float, u);
}
static __device__ __forceinline__ short f2b(float f) {
    __hip_bfloat16 h = __float2bfloat16(f);
    return __builtin_bit_cast(short, h);
}

// ---------- phase A: partition edges into 196 dst-buckets (packed 4B records) ----------
__global__ __launch_bounds__(256) void k_part(const int* __restrict__ src,
                                              const int* __restrict__ dst,
                                              int* __restrict__ g_cursor,
                                              int* __restrict__ ebuf) {
    __shared__ int hist[NBUCKET];
    __shared__ int base[NBUCKET];
    __shared__ int pos[NBUCKET];
    int tid = threadIdx.x;
    if (tid < NBUCKET) { hist[tid] = 0; pos[tid] = 0; }
    __syncthreads();

    int4 s[4], d[4];
    bool valid[4];
#pragma unroll
    for (int q = 0; q < 4; ++q) {
        int idx = blockIdx.x * 1024 + q * 256 + tid;    // int4 index, 4 edges each
        valid[q] = (idx < N_EDGES / 4);
        if (valid[q]) {
            s[q] = ((const int4*)src)[idx];
            d[q] = ((const int4*)dst)[idx];
        }
    }
#pragma unroll
    for (int q = 0; q < 4; ++q) {
        if (valid[q]) {
            atomicAdd(&hist[d[q].x >> 8], 1);
            atomicAdd(&hist[d[q].y >> 8], 1);
            atomicAdd(&hist[d[q].z >> 8], 1);
            atomicAdd(&hist[d[q].w >> 8], 1);
        }
    }
    __syncthreads();
    if (tid < NBUCKET && hist[tid] > 0)
        base[tid] = atomicAdd(&g_cursor[tid], hist[tid]);
    __syncthreads();
#pragma unroll
    for (int q = 0; q < 4; ++q) {
        if (valid[q]) {
            int ss[4] = { s[q].x, s[q].y, s[q].z, s[q].w };
            int dd[4] = { d[q].x, d[q].y, d[q].z, d[q].w };
#pragma unroll
            for (int e = 0; e < 4; ++e) {
                int b = dd[e] >> 8;
                int p = base[b] + atomicAdd(&pos[b], 1);
                if (p < EBUF_CAP)
                    ebuf[b * EBUF_CAP + p] = ss[e] | ((dd[e] & 255) << 16);
            }
        }
    }
}

// ---------- phase B: one block per bucket, LDS counters, L2-local slot writes ----------
__global__ __launch_bounds__(256) void k_bucket(const int* __restrict__ ebuf,
                                                const int* __restrict__ g_cursor,
                                                int* __restrict__ cnt,
                                                unsigned short* __restrict__ slots) {
    __shared__ int lcnt[256];
    int b = blockIdx.x, tid = threadIdx.x;
    lcnt[tid] = 0;
    __syncthreads();
    int n_e = g_cursor[b];
    if (n_e > EBUF_CAP) n_e = EBUF_CAP;
    const int* eb = ebuf + b * EBUF_CAP;
    int n4 = n_e >> 2;
    for (int t = tid; t < n4; t += 256) {
        int4 v = ((const int4*)eb)[t];
        int vv[4] = { v.x, v.y, v.z, v.w };
#pragma unroll
        for (int e = 0; e < 4; ++e) {
            int dl = (vv[e] >> 16) & 255;
            int sv = vv[e] & 0xFFFF;
            int p = atomicAdd(&lcnt[dl], 1);
            if (p < SLOT_CAP) slots[(size_t)(b * 256 + dl) * SLOT_CAP + p] = (unsigned short)sv;
        }
    }
    for (int t = (n4 << 2) + tid; t < n_e; t += 256) {
        int vv = eb[t];
        int dl = (vv >> 16) & 255;
        int sv = vv & 0xFFFF;
        int p = atomicAdd(&lcnt[dl], 1);
        if (p < SLOT_CAP) slots[(size_t)(b * 256 + dl) * SLOT_CAP + p] = (unsigned short)sv;
    }
    __syncthreads();
    int nid = b * 256 + tid;
    if (nid < N_NODES) cnt[nid] = lcnt[tid];
}

// ---------- prep ----------
__global__ void k_cvt_x(const float4* __restrict__ x, short4* __restrict__ xb) {
    int i = blockIdx.x * 256 + threadIdx.x;   // N_NODES*IN_C/4 threads exactly
    float4 v = x[i];
    short4 o = { f2b(v.x), f2b(v.y), f2b(v.z), f2b(v.w) };
    xb[i] = o;
}

// Wt[n][k], n in [0,512): n<256 -> W1l[k][n], else W1r[k][n-256]
__global__ void k_prep_w(const float* __restrict__ W1l, const float* __restrict__ W1r,
                         __hip_bfloat16* __restrict__ Wt) {
    int idx = blockIdx.x * 256 + threadIdx.x;  // 512*256
    int n = idx >> 8, k = idx & 255;
    float v = (n < HID_C) ? W1l[k * HID_C + n] : W1r[k * HID_C + (n - HID_C)];
    Wt[idx] = __float2bfloat16(v);
}

// Wt2f rows 0..9 = W2l^T, rows 16..25 = W2r^T, fp32, stride 256
__global__ void k_prep_w2f(const float* __restrict__ W2l, const float* __restrict__ W2r,
                           float* __restrict__ Wt2f) {
    int idx = blockIdx.x * 256 + threadIdx.x;  // 20*256
    int r = idx >> 8, k = idx & 255;
    if (r < OUT_C) Wt2f[r * 256 + k] = W2l[k * OUT_C + r];
    else           Wt2f[(16 + r - OUT_C) * 256 + k] = W2r[k * OUT_C + (r - OUT_C)];
}

// ---------- GEMM1: [Ab | Bh] = Xb @ [W1l | W1r] (+b1 on Bh), 64x64 per wave ----------
__global__ __launch_bounds__(256) void k_gemm1(
        const __hip_bfloat16* __restrict__ Xb, const __hip_bfloat16* __restrict__ Wt,
        const float* __restrict__ b1,
        __hip_bfloat16* __restrict__ Ab, __hip_bfloat16* __restrict__ Bh) {
    int wave = threadIdx.x >> 6, lane = threadIdx.x & 63;
    int r = lane & 15, quad = lane >> 4;
    int m_base = blockIdx.x * 64;
    int n_base = blockIdx.y * 256 + wave * 64;

    const bf16x8* ap[4];
    const bf16x8* bp[4];
#pragma unroll
    for (int i = 0; i < 4; ++i) {
        int row = m_base + 16 * i + r;
        if (row > N_NODES - 1) row = N_NODES - 1;
        ap[i] = (const bf16x8*)(Xb + (size_t)row * IN_C + quad * 8);
        bp[i] = (const bf16x8*)(Wt + (size_t)(n_base + 16 * i + r) * IN_C + quad * 8);
    }
    f32x4 acc[4][4];
#pragma unroll
    for (int i = 0; i < 4; ++i)
#pragma unroll
        for (int j = 0; j < 4; ++j) acc[i][j] = f32x4{0.f, 0.f, 0.f, 0.f};

#pragma unroll
    for (int kk = 0; kk < IN_C / 32; ++kk) {
        bf16x8 a[4], b[4];
#pragma unroll
        for (int i = 0; i < 4; ++i) a[i] = ap[i][kk * 4];
#pragma unroll
        for (int j = 0; j < 4; ++j) b[j] = bp[j][kk * 4];
#pragma unroll
        for (int i = 0; i < 4; ++i)
#pragma unroll
            for (int j = 0; j < 4; ++j)
                acc[i][j] = __builtin_amdgcn_mfma_f32_16x16x32_bf16(a[i], b[j], acc[i][j], 0, 0, 0);
    }

    bool left = (n_base < HID_C);  // block-uniform
#pragma unroll
    for (int j = 0; j < 4; ++j) {
        int col = n_base + 16 * j + r;
        float bias = left ? 0.f : b1[col - HID_C];
#pragma unroll
        for (int i = 0; i < 4; ++i) {
#pragma unroll
            for (int ii = 0; ii < 4; ++ii) {
                int row = m_base + 16 * i + quad * 4 + ii;
                if (row < N_NODES) {
                    float v = acc[i][j][ii];
                    if (left) Ab[(size_t)row * HID_C + col] = __float2bfloat16(v);
                    else      Bh[(size_t)row * HID_C + (col - HID_C)] = __float2bfloat16(v + bias);
                }
            }
        }
    }
}

// ---------- fused: layer1 mean-agg + relu + GEMM2 epilogue -> CD ----------
// half-wave = contiguous half of edge list; 4-deep unroll -> 8 gathers in flight/wave
__global__ __launch_bounds__(256) void k_agg1f(
        const __hip_bfloat16* __restrict__ Ab, const __hip_bfloat16* __restrict__ Bh,
        const int* __restrict__ cnt, const unsigned short* __restrict__ slots,
        const float* __restrict__ Wt2f, const float* __restrict__ b2,
        float* __restrict__ CD) {
    int wave = threadIdx.x >> 6, lane = threadIdx.x & 63;
    int nid = blockIdx.x * 4 + wave;          // grid 12500 -> exact
    int half = lane >> 5;
    int c8 = (lane & 31) * 8;
    const unsigned short* row = slots + (size_t)nid * SLOT_CAP;
    int n = cnt[nid];
    if (n > SLOT_CAP) n = SLOT_CAP;
    int mid = (n + 1) >> 1;
    int beg = half ? mid : 0;
    int end = half ? n : mid;

    float s0[8], s1[8], s2[8], s3[8];
#pragma unroll
    for (int j = 0; j < 8; ++j) { s0[j] = 0.f; s1[j] = 0.f; s2[j] = 0.f; s3[j] = 0.f; }

    const __hip_bfloat16* abc = Ab + c8;
    int e = beg;
    for (; e + 4 <= end; e += 4) {
        int i0 = row[e], i1 = row[e + 1], i2 = row[e + 2], i3 = row[e + 3];
        bf16x8 v0 = *(const bf16x8*)(abc + (size_t)i0 * HID_C);
        bf16x8 v1 = *(const bf16x8*)(abc + (size_t)i1 * HID_C);
        bf16x8 v2 = *(const bf16x8*)(abc + (size_t)i2 * HID_C);
        bf16x8 v3 = *(const bf16x8*)(abc + (size_t)i3 * HID_C);
#pragma unroll
        for (int j = 0; j < 8; ++j) {
            s0[j] += b2f(v0[j]); s1[j] += b2f(v1[j]);
            s2[j] += b2f(v2[j]); s3[j] += b2f(v3[j]);
        }
    }
    for (; e < end; ++e) {
        int i0 = row[e];
        bf16x8 v0 = *(const bf16x8*)(abc + (size_t)i0 * HID_C);
#pragma unroll
        for (int j = 0; j < 8; ++j) s0[j] += b2f(v0[j]);
    }
#pragma unroll
    for (int j = 0; j < 8; ++j) s0[j] += (s1[j] + s2[j]) + s3[j];
#pragma unroll
    for (int j = 0; j < 8; ++j) s0[j] += __shfl_down(s0[j], 32, 64);

    // h = relu(mean + Bh) computed on half0, broadcast to half1
    float h[8];
    float inv = 1.f / fmaxf((float)n, 1.f);
    if (half == 0) {
        bf16x8 bb = *(const bf16x8*)(Bh + (size_t)nid * HID_C + c8);
#pragma unroll
        for (int j = 0; j < 8; ++j)
            h[j] = fmaxf(s0[j] * inv + b2f(bb[j]), 0.f);
    }
#pragma unroll
    for (int j = 0; j < 8; ++j) h[j] = __shfl(h[j], lane & 31, 64);

    // 10 dot products with W2 (fp32), reduce over 32 lanes of this half
    const float* wbase = Wt2f + (half ? 16 * 256 : 0);
    float acc[10];
#pragma unroll
    for (int j = 0; j < 10; ++j) {
        f32x4 w0 = *(const f32x4*)(wbase + j * 256 + c8);
        f32x4 w1 = *(const f32x4*)(wbase + j * 256 + c8 + 4);
        float a = h[0] * w0[0] + h[1] * w0[1] + h[2] * w0[2] + h[3] * w0[3]
                + h[4] * w1[0] + h[5] * w1[1] + h[6] * w1[2] + h[7] * w1[3];
#pragma unroll
        for (int off = 16; off > 0; off >>= 1)
            a += __shfl_down(a, off, 32);
        acc[j] = a;
    }
    if ((lane & 31) == 0) {
        float* o = CD + (size_t)nid * CD_STRIDE + half * 16;
        if (half == 0) {
#pragma unroll
            for (int j = 0; j < 10; ++j) o[j] = acc[j];
            o[10] = 0.f; o[11] = 0.f;
        } else {
#pragma unroll
            for (int j = 0; j < 10; ++j) o[j] = acc[j] + b2[j];
        }
    }
}

// ---------- layer2 aggregation + log_softmax: two nodes per wave (32 lanes each) ----------
__global__ __launch_bounds__(256) void k_agg2(
        const float* __restrict__ CD, const int* __restrict__ cnt,
        const unsigned short* __restrict__ slots, float* __restrict__ out) {
    int wave = threadIdx.x >> 6, lane = threadIdx.x & 63;
    int half = lane >> 5, sub = lane & 31;
    int nid = blockIdx.x * 8 + wave * 2 + half;   // grid 6250 -> exact
    const unsigned short* row = slots + (size_t)nid * SLOT_CAP;
    int n = cnt[nid];
    if (n > SLOT_CAP) n = SLOT_CAP;
    float s[10];
#pragma unroll
    for (int j = 0; j < 10; ++j) s[j] = 0.f;
    for (int e = sub; e < n; e += 32) {
        const float* cr = CD + (size_t)row[e] * CD_STRIDE;
        f32x4 v0 = *(const f32x4*)cr;
        f32x4 v1 = *(const f32x4*)(cr + 4);
        f32x4 v2 = *(const f32x4*)(cr + 8);   // cols 8..11 (10,11 zeroed)
#pragma unroll
        for (int j = 0; j < 4; ++j) { s[j] += v0[j]; s[4 + j] += v1[j]; }
        s[8] += v2[0]; s[9] += v2[1];
    }
#pragma unroll
    for (int j = 0; j < 10; ++j)
#pragma unroll
        for (int off = 16; off > 0; off >>= 1)
            s[j] += __shfl_down(s[j], off, 32);
    if (sub == 0) {
        float inv = 1.f / fmaxf((float)n, 1.f);
        float z[10], mx = -1e30f;
#pragma unroll
        for (int j = 0; j < 10; ++j) {
            z[j] = s[j] * inv + CD[(size_t)nid * CD_STRIDE + 16 + j];
            mx = fmaxf(mx, z[j]);
        }
        float se = 0.f;
#pragma unroll
        for (int j = 0; j < 10; ++j) se += expf(z[j] - mx);
        float lse = logf(se) + mx;
#pragma unroll
        for (int j = 0; j < 10; ++j) out[(size_t)nid * OUT_C + j] = z[j] - lse;
    }
}

extern "C" void kernel_launch(void* const* d_in, const int* in_sizes, int n_in,
                              void* d_out, int out_size, void* d_ws, size_t ws_size,
                              hipStream_t stream) {
    const float* x   = (const float*)d_in[0];
    const int*   ei  = (const int*)d_in[1];
    const float* W1l = (const float*)d_in[2];
    const float* W1r = (const float*)d_in[3];
    const float* b1  = (const float*)d_in[4];
    const float* W2l = (const float*)d_in[5];
    const float* W2r = (const float*)d_in[6];
    const float* b2  = (const float*)d_in[7];
    float* out = (float*)d_out;
    const int* src = ei;
    const int* dst = ei + N_EDGES;

    char* w = (char*)d_ws;
    size_t off = 0;
    auto alloc = [&](size_t bytes) -> void* {
        void* p = w + off;
        off = (off + bytes + 255) & ~(size_t)255;
        return p;
    };
    __hip_bfloat16* Xb   = (__hip_bfloat16*)alloc((size_t)N_NODES * IN_C * 2);
    __hip_bfloat16* Wt   = (__hip_bfloat16*)alloc((size_t)2 * HID_C * IN_C * 2);
    float*          Wt2f = (float*)alloc((size_t)32 * 256 * 4);
    __hip_bfloat16* Ab   = (__hip_bfloat16*)alloc((size_t)N_NODES * HID_C * 2);
    __hip_bfloat16* Bh   = (__hip_bfloat16*)alloc((size_t)N_NODES * HID_C * 2);
    float* CD = (float*)alloc((size_t)N_NODES * CD_STRIDE * 4);
    int* cnt      = (int*)alloc((size_t)N_NODES * 4);
    unsigned short* slots = (unsigned short*)alloc((size_t)N_NODES * SLOT_CAP * 2);
    int* g_cursor = (int*)alloc((size_t)NBUCKET * 4);
    int* ebuf     = (int*)alloc((size_t)NBUCKET * EBUF_CAP * 4);

    hipMemsetAsync(g_cursor, 0, (size_t)NBUCKET * 4, stream);

    k_part<<<(N_EDGES / 4 + 1023) / 1024, 256, 0, stream>>>(src, dst, g_cursor, ebuf);
    k_bucket<<<NBUCKET, 256, 0, stream>>>(ebuf, g_cursor, cnt, slots);

    k_cvt_x<<<(N_NODES * IN_C / 4) / 256, 256, 0, stream>>>((const float4*)x, (short4*)Xb);
    k_prep_w<<<512, 256, 0, stream>>>(W1l, W1r, Wt);
    k_prep_w2f<<<20, 256, 0, stream>>>(W2l, W2r, Wt2f);

    k_gemm1<<<dim3((N_NODES + 63) / 64, 2), 256, 0, stream>>>(Xb, Wt, b1, Ab, Bh);
    k_agg1f<<<N_NODES / 4, 256, 0, stream>>>(Ab, Bh, cnt, slots, Wt2f, b2, CD);
    k_agg2<<<N_NODES / 8, 256, 0, stream>>>(CD, cnt, slots, out);
}